// Round 1
// baseline (51432.788 us; speedup 1.0000x reference)
//
#include <hip/hip_runtime.h>

#define DEVFN __device__ __forceinline__

// tanh(x) = sign(x) * (1 - e^{-2|x|}) / (1 + e^{-2|x|}); exact formula, ~2-3 ulp
DEVFN float fast_tanh(float v) {
    float ax = fabsf(v);
    float t  = __builtin_amdgcn_exp2f(ax * -2.8853900817779268f);  // exp(-2*ax)
    float r  = (1.0f - t) * __builtin_amdgcn_rcpf(1.0f + t);
    return copysignf(r, v);
}

static constexpr int B = 64, U = 4096, H = 64;
static constexpr int N = B * U;  // 262144 sequential steps

// permlane swap builtins return: unsigned int vector of 2 (index with [0]/[1])
typedef unsigned int v2u __attribute__((__vector_size__(2 * sizeof(unsigned int))));

// ============================================================================
// Kernel 1: parallel input projection (unchanged — noise at this scale).
// ============================================================================
__global__ __launch_bounds__(64) void proj_kernel(
    const int*   __restrict__ y,      // [B][U]
    const float* __restrict__ emb,    // [V][H]
    const float* __restrict__ W_ih,   // [H][H]
    const float* __restrict__ b_ih,
    const float* __restrict__ b_hh,
    float*       __restrict__ xout)   // [N][H]
{
    __shared__ __align__(16) float e_s[64][H];
    __shared__ int ids_s[64];
    const int l    = threadIdx.x;          // 0..63
    const int row0 = blockIdx.x * 64;

    float w[H];
    #pragma unroll
    for (int k4 = 0; k4 < 16; ++k4) {
        float4 v = *(const float4*)&W_ih[l * H + k4 * 4];
        w[k4*4+0] = v.x; w[k4*4+1] = v.y; w[k4*4+2] = v.z; w[k4*4+3] = v.w;
    }
    const float bias = b_ih[l] + b_hh[l];

    {
        int i = row0 + l;
        ids_s[l] = y[(i & (B - 1)) * U + (i >> 6)];
    }
    __syncthreads();

    #pragma unroll 4
    for (int r = 0; r < 64; ++r) {
        e_s[r][l] = emb[ids_s[r] * H + l];
    }
    __syncthreads();

    #pragma unroll 1
    for (int r = 0; r < 64; ++r) {
        float acc0 = bias, acc1 = 0.f;
        #pragma unroll
        for (int k4 = 0; k4 < 16; ++k4) {
            float4 ev = *(const float4*)&e_s[r][k4 * 4];
            acc0 = fmaf(ev.x, w[k4*4+0], acc0);
            acc1 = fmaf(ev.y, w[k4*4+1], acc1);
            acc0 = fmaf(ev.z, w[k4*4+2], acc0);
            acc1 = fmaf(ev.w, w[k4*4+3], acc1);
        }
        xout[(row0 + r) * H + l] = acc0 + acc1;
    }
}

// ============================================================================
// Kernel 2: sequential scan, one wave. R6 changes (theory: the ~300 cyc/step
// fixed residue is (a) per-step store->load VMEM ordering on the aliased
// in-place buffer and/or (b) 16-deep DPP-fmac dependency chains):
//   1. h is staged in a 16 KB LDS ring (ds_write, lgkm counter) and flushed
//      to global in 64-row bursts -> the per-step VM stream is ONLY the
//      prefetch load; LDS cannot alias global, so no conservative waitcnt
//      can serialize the loop. x' also moved to d_ws when it fits.
//   2. 16 accumulation chains (depth 4) instead of 4 (depth 16). Chain
//      entries are v_mul_f32_dpp with a dummy asm dependency on the block's
//      plain R=0 op -> guaranteed >=2-instr spacing from the permlane
//      writes of hb* (DPP read-after-VALU-write hazard), zero cycle cost.
// ============================================================================

// ---- 64 named weights: wB_R = W_hh[j][16*B + ((j - R) & 15)] ----
#define DW(Bk, R) float w##Bk##_##R = W_hh[j * H + (Bk) * 16 + (((j & 15) - (R)) & 15)];
#define DWBLK(Bk) DW(Bk,0) DW(Bk,1) DW(Bk,2) DW(Bk,3) DW(Bk,4) DW(Bk,5) DW(Bk,6) DW(Bk,7) \
                  DW(Bk,8) DW(Bk,9) DW(Bk,10) DW(Bk,11) DW(Bk,12) DW(Bk,13) DW(Bk,14) DW(Bk,15)

// ---- broadcast h -> 4 block-replicated registers (VALU-only) ----
#define BCAST(h)                                                                     \
    const unsigned hbits = (unsigned)__float_as_int(h);                              \
    v2u p  = __builtin_amdgcn_permlane32_swap(hbits, hbits, false, false);           \
    v2u q0 = __builtin_amdgcn_permlane16_swap(p[0], p[0], false, false);             \
    v2u q1 = __builtin_amdgcn_permlane16_swap(p[1], p[1], false, false);             \
    float hb0 = __int_as_float((int)q0[0]), hb1 = __int_as_float((int)q0[1]);        \
    float hb2 = __int_as_float((int)q1[0]), hb3 = __int_as_float((int)q1[1]);

// ---- fused DPP MAC: acc += rotate16(hb, R) * w ----
#define FMAC_DPP(ACC, HB, W, R)                                              \
    asm("v_fmac_f32_dpp %0, %1, %2 row_ror:" #R " row_mask:0xf bank_mask:0xf"\
        : "+v"(ACC) : "v"(HB), "v"(W))

// ---- chain entry: dst = rotate16(hb, R) * w; AFTER is a scheduling-only
//      dependency that pins this DPP read >=2 instrs past the permlane writes
#define FMUL_DPP_ORD(DST, HB, W, R, AFTER)                                   \
    asm("v_mul_f32_dpp %0, %1, %2 row_ror:" #R " row_mask:0xf bank_mask:0xf" \
        : "=v"(DST) : "v"(HB), "v"(W), "v"(AFTER))

// ---- round R entering chain C (4 blocks) ----
#define FRM(R, C)                                          \
    FMUL_DPP_ORD(a0##C, hb0, w0_##R, R, a00);              \
    FMUL_DPP_ORD(a1##C, hb1, w1_##R, R, a10);              \
    FMUL_DPP_ORD(a2##C, hb2, w2_##R, R, a20);              \
    FMUL_DPP_ORD(a3##C, hb3, w3_##R, R, a30);

// ---- round R accumulating into chain C (4 blocks) ----
#define FRC(R, C)                                          \
    FMAC_DPP(a0##C, hb0, w0_##R, R);                       \
    FMAC_DPP(a1##C, hb1, w1_##R, R);                       \
    FMAC_DPP(a2##C, hb2, w2_##R, R);                       \
    FMAC_DPP(a3##C, hb3, w3_##R, R);

// ---- one recurrence step; 16 chains of depth 4, output to LDS ring ----
#define SLOT(XF, IDX, PFETCH) {                                              \
    BCAST(h)                                                                 \
    float a00 = fmaf(hb0, w0_0, XF);   /* plain R=0 ops: chain-0 entries */  \
    float a10 = hb1 * w1_0;            /* and the >=2-instr hazard gap   */  \
    float a20 = hb2 * w2_0;            /* between permlane writes of hb* */  \
    float a30 = hb3 * w3_0;            /* and the first DPP reads        */  \
    float a01, a11, a21, a31, a02, a12, a22, a32, a03, a13, a23, a33;        \
    FRM(1, 1)  FRM(2, 2)  FRM(3, 3)                                          \
    FRC(4, 0)  FRC(5, 1)  FRC(6, 2)  FRC(7, 3)                               \
    FRC(8, 0)  FRC(9, 1)  FRC(10, 2) FRC(11, 3)                              \
    FRC(12, 0) FRC(13, 1) FRC(14, 2) FRC(15, 3)                              \
    float s0 = (a00 + a01) + (a02 + a03);                                    \
    float s1 = (a10 + a11) + (a12 + a13);                                    \
    float s2 = (a20 + a21) + (a22 + a23);                                    \
    float s3 = (a30 + a31) + (a32 + a33);                                    \
    h = fast_tanh((s0 + s1) + (s2 + s3));                                    \
    ringrow[(IDX) * H + j] = h;        /* ds_write_b32: lgkm, not vmcnt */   \
    PFETCH                                                                   \
}

// ---- flush 64 ring rows [base, base+64) to global (base % 64 == 0) ----
#define RING_FLUSH(BASE) {                                                   \
    const int fbase = (BASE);                                                \
    _Pragma("unroll")                                                        \
    for (int t = 0; t < 16; ++t) {                                           \
        const int idx = t * 64 + j;                                          \
        const int row = idx >> 4;                                            \
        const int c4  = (idx & 15) * 4;                                      \
        const float4 v = *(const float4*)&ring[row][c4];                     \
        *(float4*)&xout[(size_t)(fbase + row) * H + c4] = v;                 \
    }                                                                        \
}

__global__ __launch_bounds__(64, 1) void scan_kernel(
    const float* __restrict__ W_hh,   // [H][H]
    const float* __restrict__ h0,     // [H]
    const float* __restrict__ xin,    // [N][H]  (x' staging buffer)
    float*       __restrict__ xout)   // [N][H]  (final output)
{
    const int j = threadIdx.x;        // 0..63
    __shared__ __align__(16) float ring[64][H];   // 16 KB output staging ring

    DWBLK(0) DWBLK(1) DWBLK(2) DWBLK(3)   // 64 scalar weights -> VGPRs

    float h = h0[j];

    const float* xp = xin + j;        // lane j's element of row 0

    // 8-deep named prefetch ring: rows 0..7
    float x0 = xp[0*H], x1 = xp[1*H], x2 = xp[2*H], x3 = xp[3*H];
    float x4 = xp[4*H], x5 = xp[5*H], x6 = xp[6*H], x7 = xp[7*H];
    xp += 8 * H;                      // xp now points at row i+8

    #pragma unroll 1
    for (int i = 0; i < N - 8; i += 8) {
        float* ringrow = &ring[i & 63][0];
        SLOT(x0, 0, x0 = xp[0*H];)
        SLOT(x1, 1, x1 = xp[1*H];)
        SLOT(x2, 2, x2 = xp[2*H];)
        SLOT(x3, 3, x3 = xp[3*H];)
        SLOT(x4, 4, x4 = xp[4*H];)
        SLOT(x5, 5, x5 = xp[5*H];)
        SLOT(x6, 6, x6 = xp[6*H];)
        SLOT(x7, 7, x7 = xp[7*H];)
        xp += 8 * H;
        if (((i + 8) & 63) == 0) {            // every 64 rows: bulk flush
            RING_FLUSH(i + 8 - 64);
        }
    }
    {   // epilogue: last 8 rows, no prefetch (ring slots 56..63)
        float* ringrow = &ring[(N - 8) & 63][0];
        SLOT(x0, 0, ) SLOT(x1, 1, ) SLOT(x2, 2, ) SLOT(x3, 3, )
        SLOT(x4, 4, ) SLOT(x5, 5, ) SLOT(x6, 6, ) SLOT(x7, 7, )
    }
    RING_FLUSH(N - 64);                       // final 64 rows
}

// ============================================================================
extern "C" void kernel_launch(void* const* d_in, const int* in_sizes, int n_in,
                              void* d_out, int out_size, void* d_ws, size_t ws_size,
                              hipStream_t stream) {
    const int*   y    = (const int*)  d_in[0];
    const float* emb  = (const float*)d_in[1];
    const float* W_ih = (const float*)d_in[2];
    const float* W_hh = (const float*)d_in[3];
    const float* b_ih = (const float*)d_in[4];
    const float* b_hh = (const float*)d_in[5];
    const float* h0   = (const float*)d_in[6];
    float* out = (float*)d_out;

    // Stage x' in the workspace when it fits (decouples scan input/output
    // buffers -> restrict is honest and runtime aliasing is gone). Fallback
    // to in-place in d_out (still correct: reads run 8+ rows ahead of the
    // 64-row-lagged flush writes).
    float* xbuf = (d_ws && ws_size >= (size_t)N * H * sizeof(float))
                      ? (float*)d_ws : out;

    proj_kernel<<<dim3(N / 64), dim3(64), 0, stream>>>(y, emb, W_ih, b_ih, b_hh, xbuf);
    scan_kernel<<<dim3(1), dim3(64), 0, stream>>>(W_hh, h0, xbuf, out);
}

// Round 2
// 48371.494 us; speedup vs baseline: 1.0633x; 1.0633x over previous
//
#include <hip/hip_runtime.h>

#define DEVFN __device__ __forceinline__

// tanh(x) = sign(x) * (1 - e^{-2|x|}) / (1 + e^{-2|x|}); exact formula, ~2-3 ulp
DEVFN float fast_tanh(float v) {
    float ax = fabsf(v);
    float t  = __builtin_amdgcn_exp2f(ax * -2.8853900817779268f);  // exp(-2*ax)
    float r  = (1.0f - t) * __builtin_amdgcn_rcpf(1.0f + t);
    return copysignf(r, v);
}

static constexpr int B = 64, U = 4096, H = 64;
static constexpr int N = B * U;  // 262144 sequential steps

// permlane swap builtins return: unsigned int vector of 2 (index with [0]/[1])
typedef unsigned int v2u __attribute__((__vector_size__(2 * sizeof(unsigned int))));

// ============================================================================
// Kernel 1: parallel input projection (unchanged — noise at this scale).
// ============================================================================
__global__ __launch_bounds__(64) void proj_kernel(
    const int*   __restrict__ y,      // [B][U]
    const float* __restrict__ emb,    // [V][H]
    const float* __restrict__ W_ih,   // [H][H]
    const float* __restrict__ b_ih,
    const float* __restrict__ b_hh,
    float*       __restrict__ xout)   // [N][H]
{
    __shared__ __align__(16) float e_s[64][H];
    __shared__ int ids_s[64];
    const int l    = threadIdx.x;          // 0..63
    const int row0 = blockIdx.x * 64;

    float w[H];
    #pragma unroll
    for (int k4 = 0; k4 < 16; ++k4) {
        float4 v = *(const float4*)&W_ih[l * H + k4 * 4];
        w[k4*4+0] = v.x; w[k4*4+1] = v.y; w[k4*4+2] = v.z; w[k4*4+3] = v.w;
    }
    const float bias = b_ih[l] + b_hh[l];

    {
        int i = row0 + l;
        ids_s[l] = y[(i & (B - 1)) * U + (i >> 6)];
    }
    __syncthreads();

    #pragma unroll 4
    for (int r = 0; r < 64; ++r) {
        e_s[r][l] = emb[ids_s[r] * H + l];
    }
    __syncthreads();

    #pragma unroll 1
    for (int r = 0; r < 64; ++r) {
        float acc0 = bias, acc1 = 0.f;
        #pragma unroll
        for (int k4 = 0; k4 < 16; ++k4) {
            float4 ev = *(const float4*)&e_s[r][k4 * 4];
            acc0 = fmaf(ev.x, w[k4*4+0], acc0);
            acc1 = fmaf(ev.y, w[k4*4+1], acc1);
            acc0 = fmaf(ev.z, w[k4*4+2], acc0);
            acc1 = fmaf(ev.w, w[k4*4+3], acc1);
        }
        xout[(row0 + r) * H + l] = acc0 + acc1;
    }
}

// ============================================================================
// Kernel 2 (R7): 4-wave cooperative scan. Theory: a single wave issues at
// ~1 instr / 4 cyc (GCN cadence) -> R6's ~95 instr/step = ~470 cyc/step is
// issue-bound. Split the 64x64 matvec across 4 waves (one per SIMD):
//   wave w, lane l: output j = 16w + (l&15), k-block = 16*(l>>4).
//   r[l] = h_prev[l] (read from LDS ring row). DPP row_ror:R gives
//   h[16*(l>>4) + ((l-R)&15)] -> 16 MACs cover the lane's k-block.
//   Cross row-group reduce: permlane32_swap + add, permlane16_swap + add
//   (valid in lanes 0-15, which are the writers).
//   h exchange: lanes 0-15 write the wave's 16-col slice of the ring row
//   (lanes 16-63 write a dump area to keep one uniform ds_write);
//   s_waitcnt lgkmcnt(0); s_barrier; all lanes ds_read the full row.
// The ring row doubles as output staging: each wave flushes ONLY ITS OWN
// columns every 64 steps (no extra barrier needed - own-wave LDS ordering).
// Raw s_barrier + manual lgkmcnt only: __syncthreads would drain vmcnt(0)
// and kill the 8-deep x-prefetch.
// ============================================================================

// ---- 16 weights per lane: w_R = W_hh[jo][kb + ((l15 - R) & 15)] ----
#define DW(R) const float w_##R = W_hh[jo * H + kb + (((l & 15) - (R)) & 15)];

// ---- fused DPP MAC: acc += rotate16(hb, R) * w ----
#define FMAC_DPP(ACC, HB, W, R)                                              \
    asm("v_fmac_f32_dpp %0, %1, %2 row_ror:" #R " row_mask:0xf bank_mask:0xf"\
        : "+v"(ACC) : "v"(HB), "v"(W))

// ---- chain entry: dst = rotate16(hb, R) * w; AFTER = scheduling dep ----
#define FMUL_DPP_ORD(DST, HB, W, R, AFTER)                                   \
    asm("v_mul_f32_dpp %0, %1, %2 row_ror:" #R " row_mask:0xf bank_mask:0xf" \
        : "=v"(DST) : "v"(HB), "v"(W), "v"(AFTER))

// ---- one recurrence step (slot = base-of-rm/wp + UU) ----
#define STEP(XV, UU, PF) {                                                   \
    float a0 = r * w_0;                                                      \
    float a1, a2, a3;                                                        \
    FMUL_DPP_ORD(a1, r, w_1, 1, a0);                                         \
    FMUL_DPP_ORD(a2, r, w_2, 2, a0);                                         \
    FMUL_DPP_ORD(a3, r, w_3, 3, a0);                                         \
    FMAC_DPP(a0, r, w_4, 4);   FMAC_DPP(a1, r, w_5, 5);                      \
    FMAC_DPP(a2, r, w_6, 6);   FMAC_DPP(a3, r, w_7, 7);                      \
    FMAC_DPP(a0, r, w_8, 8);   FMAC_DPP(a1, r, w_9, 9);                      \
    FMAC_DPP(a2, r, w_10, 10); FMAC_DPP(a3, r, w_11, 11);                    \
    FMAC_DPP(a0, r, w_12, 12); FMAC_DPP(a1, r, w_13, 13);                    \
    FMAC_DPP(a2, r, w_14, 14); FMAC_DPP(a3, r, w_15, 15);                    \
    float sum = (a0 + a1) + (a2 + a3);                                       \
    unsigned sb_ = (unsigned)__float_as_int(sum);                            \
    v2u t_ = __builtin_amdgcn_permlane32_swap(sb_, sb_, false, false);       \
    float z1 = sum + __int_as_float((int)t_[1]);   /* rows0,1: r02,r13 */    \
    unsigned zb_ = (unsigned)__float_as_int(z1);                             \
    v2u u_ = __builtin_amdgcn_permlane16_swap(zb_, zb_, false, false);       \
    float z2 = z1 + __int_as_float((int)u_[1]);    /* row0: full sum */      \
    float hn = fast_tanh(z2 + (XV));                                         \
    wp[(UU) * 64] = hn;                /* lanes<16: ring slice; else dump */ \
    PF                                                                       \
    asm volatile("s_waitcnt lgkmcnt(0)" ::: "memory");                       \
    __builtin_amdgcn_s_barrier();                                            \
    asm volatile("" ::: "memory");                                           \
    r = rm[(UU) * 64];                 /* full new h row */                  \
}

#define GRP8_PF {                                \
    STEP(x0, 0, x0 = xp[0*H];)                   \
    STEP(x1, 1, x1 = xp[1*H];)                   \
    STEP(x2, 2, x2 = xp[2*H];)                   \
    STEP(x3, 3, x3 = xp[3*H];)                   \
    STEP(x4, 4, x4 = xp[4*H];)                   \
    STEP(x5, 5, x5 = xp[5*H];)                   \
    STEP(x6, 6, x6 = xp[6*H];)                   \
    STEP(x7, 7, x7 = xp[7*H];)                   \
    xp += 8*H; rm += 512; wp += 512;             \
}

// flush: wave stores ONLY its own 16 columns of 64 staged rows
#define FLUSH(SBASE) {                                                       \
    _Pragma("unroll")                                                        \
    for (int tt = 0; tt < 4; ++tt) {                                         \
        const int row_ = tt*16 + frow;                                       \
        const float4 vv = *(const float4*)&lds[0][row_][fcol];               \
        *(float4*)&xout[((size_t)(SBASE) + row_) * H + fcol] = vv;           \
    }                                                                        \
}

__global__ __launch_bounds__(256, 1) void scan_kernel(
    const float* __restrict__ W_hh,   // [H][H]
    const float* __restrict__ h0,     // [H]
    const float* __restrict__ xin,    // [N][H]  (x' staging buffer)
    float*       __restrict__ xout)   // [N][H]  (final output)
{
    const int tid = threadIdx.x;
    const int w4  = tid >> 6;         // wave 0..3
    const int l   = tid & 63;         // lane 0..63
    const int jo  = 16 * w4 + (l & 15);   // this lane's output index
    const int kb  = 16 * (l >> 4);        // this lane's k-block base

    // [0] = 64-row h-ring (exchange + output staging), [1] = write dump
    __shared__ __align__(16) float lds[2][64][64];
    float* lflat = &lds[0][0][0];
    float* rm0 = lflat + l;                                        // read: ring[s][l]
    float* wp0 = lflat + ((l < 16) ? jo : (4096 + (l - 16)));      // write: slice/dump
    const int fcol = 16 * w4 + (l & 3) * 4;   // flush column (own slice)
    const int frow = l >> 2;                  // flush row-within-16

    DW(0)  DW(1)  DW(2)  DW(3)  DW(4)  DW(5)  DW(6)  DW(7)
    DW(8)  DW(9)  DW(10) DW(11) DW(12) DW(13) DW(14) DW(15)

    // prologue: h_{-1} = h0 into ring slot 63
    {
        float hv = h0[jo];
        wp0[63 * 64] = hv;
        asm volatile("s_waitcnt lgkmcnt(0)" ::: "memory");
        __builtin_amdgcn_s_barrier();
        asm volatile("" ::: "memory");
    }
    float r = rm0[63 * 64];           // r[l] = h0[l]

    const float* xp = xin + jo;       // lane's x element per row
    float x0 = xp[0*H], x1 = xp[1*H], x2 = xp[2*H], x3 = xp[3*H];
    float x4 = xp[4*H], x5 = xp[5*H], x6 = xp[6*H], x7 = xp[7*H];
    xp += 8 * H;

    #pragma unroll 1
    for (int sb = 0; sb < N/64 - 1; ++sb) {
        float* rm = rm0;
        float* wp = wp0;
        #pragma unroll 1
        for (int m8 = 0; m8 < 8; ++m8) { GRP8_PF }
        FLUSH((size_t)sb * 64);
    }
    {   // last superblock: final 8 steps have no prefetch (avoid OOB reads)
        float* rm = rm0;
        float* wp = wp0;
        #pragma unroll 1
        for (int m8 = 0; m8 < 7; ++m8) { GRP8_PF }
        STEP(x0, 0, ) STEP(x1, 1, ) STEP(x2, 2, ) STEP(x3, 3, )
        STEP(x4, 4, ) STEP(x5, 5, ) STEP(x6, 6, ) STEP(x7, 7, )
        FLUSH((size_t)(N/64 - 1) * 64);
    }
}

// ============================================================================
extern "C" void kernel_launch(void* const* d_in, const int* in_sizes, int n_in,
                              void* d_out, int out_size, void* d_ws, size_t ws_size,
                              hipStream_t stream) {
    const int*   y    = (const int*)  d_in[0];
    const float* emb  = (const float*)d_in[1];
    const float* W_ih = (const float*)d_in[2];
    const float* W_hh = (const float*)d_in[3];
    const float* b_ih = (const float*)d_in[4];
    const float* b_hh = (const float*)d_in[5];
    const float* h0   = (const float*)d_in[6];
    float* out = (float*)d_out;

    // Stage x' in the workspace when it fits; fallback to in-place in d_out
    // (safe: x row i is consumed/prefetched before the 64-row-lagged flush
    // ever writes row i).
    float* xbuf = (d_ws && ws_size >= (size_t)N * H * sizeof(float))
                      ? (float*)d_ws : out;

    proj_kernel<<<dim3(N / 64), dim3(64), 0, stream>>>(y, emb, W_ih, b_ih, b_hh, xbuf);
    scan_kernel<<<dim3(1), dim3(256), 0, stream>>>(W_hh, h0, xbuf, out);
}